// Round 3
// baseline (313.199 us; speedup 1.0000x reference)
//
#include <hip/hip_runtime.h>

#define N_NODES 100000
#define OUT_CH  128
#define N_EDGES 625000

typedef short short8 __attribute__((ext_vector_type(8)));
typedef float f32x4  __attribute__((ext_vector_type(4)));

__device__ inline short f32_bf16(float f) {
    union { float f; unsigned u; } c{f};
    unsigned r = 0x7FFFu + ((c.u >> 16) & 1u);
    return (short)((c.u + r) >> 16);
}
__device__ inline float bf16_f32(short s) {
    union { unsigned u; float f; } c;
    c.u = ((unsigned)(unsigned short)s) << 16;
    return c.f;
}

// ---- B fragments (loc_w | std_w fused, mfma_f32_16x16x32_bf16 B layout) ----
__global__ void prep_b(const float* __restrict__ lw, const float* __restrict__ sw,
                       short8* __restrict__ B) {
    int g = blockIdx.x * blockDim.x + threadIdx.x;   // 4096 threads
    int lane = g & 63, nt = (g >> 6) & 15, ks = g >> 10;
    int c = nt * 16 + (lane & 15);
    int k = ks * 32 + (lane >> 4) * 8;
    const float* src = (c < OUT_CH) ? (lw + c * OUT_CH + k)
                                    : (sw + (c - OUT_CH) * OUT_CH + k);
    short8 o;
#pragma unroll
    for (int j = 0; j < 8; ++j) o[j] = f32_bf16(src[j]);
    B[(ks * 16 + nt) * 64 + lane] = o;
}

// ---- counting sort of edges by target node ----
__global__ void hist_k(const int* __restrict__ ei, int* __restrict__ counts) {
    int e = blockIdx.x * blockDim.x + threadIdx.x;
    if (e < N_EDGES) atomicAdd(&counts[ei[N_EDGES + e]], 1);
}

__global__ void scan1_k(const int* __restrict__ counts, int* __restrict__ offsets,
                        int* __restrict__ partials) {
    __shared__ int lds[1024];
    int tid = threadIdx.x;
    int e = blockIdx.x * 1024 + tid;
    int v = (e < N_NODES) ? counts[e] : 0;
    lds[tid] = v;
    __syncthreads();
    for (int off = 1; off < 1024; off <<= 1) {
        int t = (tid >= off) ? lds[tid - off] : 0;
        __syncthreads();
        lds[tid] += t;
        __syncthreads();
    }
    int incl = lds[tid];
    if (e < N_NODES) offsets[e] = incl - v;
    if (tid == 1023) partials[blockIdx.x] = incl;
}

__global__ void scan2_k(int* __restrict__ partials, int nb, int* __restrict__ offsets) {
    if (threadIdx.x == 0 && blockIdx.x == 0) {
        int run = 0;
        for (int i = 0; i < nb; ++i) { int c = partials[i]; partials[i] = run; run += c; }
        offsets[N_NODES] = N_EDGES;
    }
}

__global__ void scan3_k(int* __restrict__ offsets, const int* __restrict__ partials) {
    int e = blockIdx.x * 1024 + threadIdx.x;
    if (e < N_NODES) offsets[e] += partials[blockIdx.x];
}

__global__ void reorder_k(const int* __restrict__ ei, const float* __restrict__ en,
                          const int* __restrict__ offsets, int* __restrict__ cursors,
                          int2* __restrict__ pairs) {
    int e = blockIdx.x * blockDim.x + threadIdx.x;
    if (e >= N_EDGES) return;
    int t = ei[N_EDGES + e];
    int pos = offsets[t] + atomicAdd(&cursors[t], 1);
    int2 p; p.x = ei[e], p.y = __float_as_int(en[e]);
    pairs[pos] = p;
}

// ---- fused: segment-sum gather (LDS stage) + loc/std GEMM + bf16 z emit ----
#define ROWP 132   // 128 + 4 pad -> 528B row stride (16B aligned, bank stride 4)
__global__ __launch_bounds__(256) void enc_k(const float* __restrict__ emb,
        const int* __restrict__ offsets, const int2* __restrict__ pairs,
        const short8* __restrict__ B, const float* __restrict__ lb,
        const float* __restrict__ sb, float* __restrict__ out,
        short* __restrict__ zb, int write_zb) {
    __shared__ float lds[4 * 16 * ROWP];
    int tid = threadIdx.x, wave = tid >> 6, lane = tid & 63;
    int n0 = blockIdx.x * 64 + wave * 16;
    const float2* base = (const float2*)emb;
    float* lrow = &lds[wave * 16 * ROWP];

    // gather 16 rows (wave-private LDS region; no cross-wave sync needed)
    for (int r = 0; r < 16; ++r) {
        int node = n0 + r;
        float ax = 0.f, ay = 0.f;
        if (node < N_NODES) {
            int beg = offsets[node], end = offsets[node + 1];
            int j = beg;
            for (; j + 4 <= end; j += 4) {
                int2 p0 = pairs[j], p1 = pairs[j + 1], p2 = pairs[j + 2], p3 = pairs[j + 3];
                float2 v0 = base[(size_t)p0.x * 64 + lane];
                float2 v1 = base[(size_t)p1.x * 64 + lane];
                float2 v2 = base[(size_t)p2.x * 64 + lane];
                float2 v3 = base[(size_t)p3.x * 64 + lane];
                float n0f = __int_as_float(p0.y), n1f = __int_as_float(p1.y);
                float n2f = __int_as_float(p2.y), n3f = __int_as_float(p3.y);
                ax += v0.x * n0f + v1.x * n1f + v2.x * n2f + v3.x * n3f;
                ay += v0.y * n0f + v1.y * n1f + v2.y * n2f + v3.y * n3f;
            }
            for (; j < end; ++j) {
                int2 p = pairs[j];
                float nm = __int_as_float(p.y);
                float2 v = base[(size_t)p.x * 64 + lane];
                ax += v.x * nm; ay += v.y * nm;
            }
        }
        float2 o; o.x = ax; o.y = ay;
        ((float2*)(lrow + r * ROWP))[lane] = o;
    }

    // MFMA: A = 16 gathered rows (from LDS), B = fused weights
    int arow = lane & 15, kb = (lane >> 4) * 8;
    f32x4 acc[16];
#pragma unroll
    for (int i = 0; i < 16; ++i) acc[i] = (f32x4)(0.f);

#pragma unroll
    for (int ks = 0; ks < 4; ++ks) {
        const float* ap = &lrow[arow * ROWP + ks * 32 + kb];
        float4 a0 = *(const float4*)ap;
        float4 a1 = *(const float4*)(ap + 4);
        short8 a;
        a[0] = f32_bf16(a0.x); a[1] = f32_bf16(a0.y);
        a[2] = f32_bf16(a0.z); a[3] = f32_bf16(a0.w);
        a[4] = f32_bf16(a1.x); a[5] = f32_bf16(a1.y);
        a[6] = f32_bf16(a1.z); a[7] = f32_bf16(a1.w);
#pragma unroll
        for (int nt = 0; nt < 16; ++nt) {
            short8 b = B[(ks * 16 + nt) * 64 + lane];
            acc[nt] = __builtin_amdgcn_mfma_f32_16x16x32_bf16(a, b, acc[nt], 0, 0, 0);
        }
    }

    float* loc  = out;
    float* stdo = out + (size_t)N_NODES * OUT_CH;
    int col = lane & 15, r0 = (lane >> 4) * 4;
#pragma unroll
    for (int nt = 0; nt < 16; ++nt) {
        int c = nt * 16 + col;
        if (c < OUT_CH) {
            float bias = lb[c];
#pragma unroll
            for (int r = 0; r < 4; ++r) {
                int row = n0 + r0 + r;
                if (row < N_NODES) {
                    float v = acc[nt][r] + bias;
                    loc[(size_t)row * OUT_CH + c] = v;
                    if (write_zb) zb[(size_t)row * OUT_CH + c] = f32_bf16(v);
                }
            }
        } else {
            int cc = c - OUT_CH;
            float bias = sb[cc];
#pragma unroll
            for (int r = 0; r < 4; ++r) {
                int row = n0 + r0 + r;
                if (row < N_NODES) {
                    float x = acc[nt][r] + bias;
                    float sp = fmaxf(x, 0.f) + log1pf(expf(-fabsf(x)));
                    stdo[(size_t)row * OUT_CH + cc] = sp + 1e-10f;
                }
            }
        }
    }
}

// ---- logits from bf16 z: 16 lanes/edge, one 16B load per side ----
__global__ void logits_bf16_k(const short8* __restrict__ z, const int* __restrict__ ei,
                              float* __restrict__ lg) {
    int idx = blockIdx.x * blockDim.x + threadIdx.x;
    int e = idx >> 4, q = idx & 15;
    if (e >= N_EDGES) return;
    int s = ei[e], t = ei[N_EDGES + e];
    short8 a = z[(size_t)s * 16 + q];
    short8 b = z[(size_t)t * 16 + q];
    float d = 0.f;
#pragma unroll
    for (int i = 0; i < 8; ++i) d += bf16_f32(a[i]) * bf16_f32(b[i]);
#pragma unroll
    for (int m = 8; m >= 1; m >>= 1) d += __shfl_xor(d, m);
    if (q == 0) lg[e] = d;
}

// ---- fallback: logits from f32 loc ----
__global__ void logits_f32_k(const float* __restrict__ z, const int* __restrict__ ei,
                             float* __restrict__ lg) {
    int idx = blockIdx.x * blockDim.x + threadIdx.x;
    int e = idx >> 5, q = idx & 31;
    if (e >= N_EDGES) return;
    int s = ei[e], t = ei[N_EDGES + e];
    float4 a = *(const float4*)(z + (size_t)s * OUT_CH + q * 4);
    float4 b = *(const float4*)(z + (size_t)t * OUT_CH + q * 4);
    float d = a.x * b.x + a.y * b.y + a.z * b.z + a.w * b.w;
#pragma unroll
    for (int m = 16; m >= 1; m >>= 1) d += __shfl_xor(d, m);
    if (q == 0) lg[e] = d;
}

extern "C" void kernel_launch(void* const* d_in, const int* in_sizes, int n_in,
                              void* d_out, int out_size, void* d_ws, size_t ws_size,
                              hipStream_t stream) {
    const float* emb = (const float*)d_in[0];
    const int*   ei  = (const int*)d_in[1];
    const float* en  = (const float*)d_in[2];
    const float* lw  = (const float*)d_in[3];
    const float* lb  = (const float*)d_in[4];
    const float* sw  = (const float*)d_in[5];
    const float* sb  = (const float*)d_in[6];
    float* out = (float*)d_out;

    char* ws = (char*)d_ws;
    size_t o = 0;
    short8* B       = (short8*)(ws + o); o += 65536;
    int*    counts  = (int*)(ws + o);    o += 400128;
    int*    offsets = (int*)(ws + o);    o += 400128;   // N_NODES+1 entries
    int*    cursors = (int*)(ws + o);    o += 400128;
    int*    partials= (int*)(ws + o);    o += 1024;
    int2*   pairs   = (int2*)(ws + o);   o += (size_t)N_EDGES * 8;
    short*  zb      = (short*)(ws + o);  o += (size_t)N_NODES * OUT_CH * 2;
    int use_zb = (o <= ws_size) ? 1 : 0;

    hipMemsetAsync(counts, 0, N_NODES * sizeof(int), stream);
    hipMemsetAsync(cursors, 0, N_NODES * sizeof(int), stream);

    prep_b<<<16, 256, 0, stream>>>(lw, sw, B);
    hist_k<<<(N_EDGES + 255) / 256, 256, 0, stream>>>(ei, counts);
    scan1_k<<<98, 1024, 0, stream>>>(counts, offsets, partials);
    scan2_k<<<1, 64, 0, stream>>>(partials, 98, offsets);
    scan3_k<<<98, 1024, 0, stream>>>(offsets, partials);
    reorder_k<<<(N_EDGES + 255) / 256, 256, 0, stream>>>(ei, en, offsets, cursors, pairs);
    enc_k<<<(N_NODES + 63) / 64, 256, 0, stream>>>(emb, offsets, pairs, B, lb, sb,
                                                   out, zb, use_zb);
    float* lg = out + (size_t)2 * N_NODES * OUT_CH;
    if (use_zb)
        logits_bf16_k<<<((size_t)N_EDGES * 16 + 255) / 256, 256, 0, stream>>>(
            (const short8*)zb, ei, lg);
    else
        logits_f32_k<<<((size_t)N_EDGES * 32 + 255) / 256, 256, 0, stream>>>(out, ei, lg);
}

// Round 4
// 281.081 us; speedup vs baseline: 1.1143x; 1.1143x over previous
//
#include <hip/hip_runtime.h>

#define N_NODES 100000
#define OUT_CH  128
#define N_EDGES 625000

typedef short short8 __attribute__((ext_vector_type(8)));
typedef float f32x4  __attribute__((ext_vector_type(4)));

__device__ inline short f32_bf16(float f) {
    union { float f; unsigned u; } c{f};
    unsigned r = 0x7FFFu + ((c.u >> 16) & 1u);
    return (short)((c.u + r) >> 16);
}
__device__ inline float bf16_f32(short s) {
    union { unsigned u; float f; } c;
    c.u = ((unsigned)(unsigned short)s) << 16;
    return c.f;
}

// ---- B fragments (loc_w | std_w fused, mfma_f32_16x16x32_bf16 B layout) ----
__global__ void prep_b(const float* __restrict__ lw, const float* __restrict__ sw,
                       short8* __restrict__ B) {
    int g = blockIdx.x * blockDim.x + threadIdx.x;   // 4096 threads
    int lane = g & 63, nt = (g >> 6) & 15, ks = g >> 10;
    int c = nt * 16 + (lane & 15);
    int k = ks * 32 + (lane >> 4) * 8;
    const float* src = (c < OUT_CH) ? (lw + c * OUT_CH + k)
                                    : (sw + (c - OUT_CH) * OUT_CH + k);
    short8 o;
#pragma unroll
    for (int j = 0; j < 8; ++j) o[j] = f32_bf16(src[j]);
    B[(ks * 16 + nt) * 64 + lane] = o;
}

// ---- counting sort of edges by target node ----
__global__ void hist_k(const int* __restrict__ ei, int* __restrict__ counts) {
    int e = blockIdx.x * blockDim.x + threadIdx.x;
    if (e < N_EDGES) atomicAdd(&counts[ei[N_EDGES + e]], 1);
}

__global__ void scan1_k(const int* __restrict__ counts, int* __restrict__ offsets,
                        int* __restrict__ partials) {
    __shared__ int lds[1024];
    int tid = threadIdx.x;
    int e = blockIdx.x * 1024 + tid;
    int v = (e < N_NODES) ? counts[e] : 0;
    lds[tid] = v;
    __syncthreads();
    for (int off = 1; off < 1024; off <<= 1) {
        int t = (tid >= off) ? lds[tid - off] : 0;
        __syncthreads();
        lds[tid] += t;
        __syncthreads();
    }
    int incl = lds[tid];
    if (e < N_NODES) offsets[e] = incl - v;
    if (tid == 1023) partials[blockIdx.x] = incl;
}

__global__ void scan2_k(int* __restrict__ partials, int nb, int* __restrict__ offsets) {
    if (threadIdx.x == 0 && blockIdx.x == 0) {
        int run = 0;
        for (int i = 0; i < nb; ++i) { int c = partials[i]; partials[i] = run; run += c; }
        offsets[N_NODES] = N_EDGES;
    }
}

__global__ void scan3_k(int* __restrict__ offsets, const int* __restrict__ partials) {
    int e = blockIdx.x * 1024 + threadIdx.x;
    if (e < N_NODES) offsets[e] += partials[blockIdx.x];
}

__global__ void reorder_k(const int* __restrict__ ei, const float* __restrict__ en,
                          const int* __restrict__ offsets, int* __restrict__ cursors,
                          int2* __restrict__ pairs) {
    int e = blockIdx.x * blockDim.x + threadIdx.x;
    if (e >= N_EDGES) return;
    int t = ei[N_EDGES + e];
    int pos = offsets[t] + atomicAdd(&cursors[t], 1);
    int2 p; p.x = ei[e]; p.y = __float_as_int(en[e]);
    pairs[pos] = p;
}

// ---- segment-sum gather: one wave per node, x4 unrolled (MLP) ----
__global__ void gather_k(const float* __restrict__ emb, const int* __restrict__ offsets,
                         const int2* __restrict__ pairs, float* __restrict__ out) {
    int g = blockIdx.x * blockDim.x + threadIdx.x;
    int node = g >> 6, lane = g & 63;
    if (node >= N_NODES) return;
    int beg = offsets[node], end = offsets[node + 1];
    float ax = 0.f, ay = 0.f;
    const float2* base = (const float2*)emb;
    int j = beg;
    for (; j + 4 <= end; j += 4) {
        int2 p0 = pairs[j], p1 = pairs[j + 1], p2 = pairs[j + 2], p3 = pairs[j + 3];
        float2 v0 = base[(size_t)p0.x * 64 + lane];
        float2 v1 = base[(size_t)p1.x * 64 + lane];
        float2 v2 = base[(size_t)p2.x * 64 + lane];
        float2 v3 = base[(size_t)p3.x * 64 + lane];
        float n0f = __int_as_float(p0.y), n1f = __int_as_float(p1.y);
        float n2f = __int_as_float(p2.y), n3f = __int_as_float(p3.y);
        ax += v0.x * n0f + v1.x * n1f + v2.x * n2f + v3.x * n3f;
        ay += v0.y * n0f + v1.y * n1f + v2.y * n2f + v3.y * n3f;
    }
    for (; j < end; ++j) {
        int2 p = pairs[j];
        float nm = __int_as_float(p.y);
        float2 v = base[(size_t)p.x * 64 + lane];
        ax += v.x * nm; ay += v.y * nm;
    }
    float2 o; o.x = ax; o.y = ay;
    ((float2*)out)[(size_t)node * 64 + lane] = o;   // ptr -> loc region
}

// ---- fused loc/std GEMM in-place over ptr, emits bf16 z ----
__global__ __launch_bounds__(256) void gemm_k(float* __restrict__ out,
                                              const short8* __restrict__ B,
                                              const float* __restrict__ lb,
                                              const float* __restrict__ sb,
                                              short* __restrict__ zb, int write_zb) {
    int tid = threadIdx.x;
    int wave = tid >> 6, lane = tid & 63;
    int n0 = (blockIdx.x * 4 + wave) * 16;
    if (n0 >= N_NODES) return;

    const float* P = out;
    float* loc  = out;
    float* stdo = out + (size_t)N_NODES * OUT_CH;

    int arow = n0 + (lane & 15);
    int kb = (lane >> 4) * 8;

    f32x4 acc[16];
#pragma unroll
    for (int i = 0; i < 16; ++i) acc[i] = (f32x4)(0.f);

#pragma unroll
    for (int ks = 0; ks < 4; ++ks) {
        const float* ap = P + (size_t)arow * OUT_CH + ks * 32 + kb;
        float4 a0 = *(const float4*)ap;
        float4 a1 = *(const float4*)(ap + 4);
        short8 a;
        a[0] = f32_bf16(a0.x); a[1] = f32_bf16(a0.y);
        a[2] = f32_bf16(a0.z); a[3] = f32_bf16(a0.w);
        a[4] = f32_bf16(a1.x); a[5] = f32_bf16(a1.y);
        a[6] = f32_bf16(a1.z); a[7] = f32_bf16(a1.w);
#pragma unroll
        for (int nt = 0; nt < 16; ++nt) {
            short8 b = B[(ks * 16 + nt) * 64 + lane];
            acc[nt] = __builtin_amdgcn_mfma_f32_16x16x32_bf16(a, b, acc[nt], 0, 0, 0);
        }
    }

    int col = lane & 15, r0 = (lane >> 4) * 4;
#pragma unroll
    for (int nt = 0; nt < 16; ++nt) {
        int c = nt * 16 + col;
        if (c < OUT_CH) {
            float bias = lb[c];
#pragma unroll
            for (int r = 0; r < 4; ++r) {
                int row = n0 + r0 + r;
                if (row < N_NODES) {
                    float v = acc[nt][r] + bias;
                    loc[(size_t)row * OUT_CH + c] = v;
                    if (write_zb) zb[(size_t)row * OUT_CH + c] = f32_bf16(v);
                }
            }
        } else {
            int cc = c - OUT_CH;
            float bias = sb[cc];
#pragma unroll
            for (int r = 0; r < 4; ++r) {
                int row = n0 + r0 + r;
                if (row < N_NODES) {
                    float x = acc[nt][r] + bias;
                    float sp = fmaxf(x, 0.f) + log1pf(expf(-fabsf(x)));
                    stdo[(size_t)row * OUT_CH + cc] = sp + 1e-10f;
                }
            }
        }
    }
}

// ---- logits from bf16 z: 16 lanes/edge, one 16B load per side ----
__global__ void logits_bf16_k(const short8* __restrict__ z, const int* __restrict__ ei,
                              float* __restrict__ lg) {
    int idx = blockIdx.x * blockDim.x + threadIdx.x;
    int e = idx >> 4, q = idx & 15;
    if (e >= N_EDGES) return;
    int s = ei[e], t = ei[N_EDGES + e];
    short8 a = z[(size_t)s * 16 + q];
    short8 b = z[(size_t)t * 16 + q];
    float d = 0.f;
#pragma unroll
    for (int i = 0; i < 8; ++i) d += bf16_f32(a[i]) * bf16_f32(b[i]);
#pragma unroll
    for (int m = 8; m >= 1; m >>= 1) d += __shfl_xor(d, m);
    if (q == 0) lg[e] = d;
}

// ---- fallback: logits from f32 loc ----
__global__ void logits_f32_k(const float* __restrict__ z, const int* __restrict__ ei,
                             float* __restrict__ lg) {
    int idx = blockIdx.x * blockDim.x + threadIdx.x;
    int e = idx >> 5, q = idx & 31;
    if (e >= N_EDGES) return;
    int s = ei[e], t = ei[N_EDGES + e];
    float4 a = *(const float4*)(z + (size_t)s * OUT_CH + q * 4);
    float4 b = *(const float4*)(z + (size_t)t * OUT_CH + q * 4);
    float d = a.x * b.x + a.y * b.y + a.z * b.z + a.w * b.w;
#pragma unroll
    for (int m = 16; m >= 1; m >>= 1) d += __shfl_xor(d, m);
    if (q == 0) lg[e] = d;
}

extern "C" void kernel_launch(void* const* d_in, const int* in_sizes, int n_in,
                              void* d_out, int out_size, void* d_ws, size_t ws_size,
                              hipStream_t stream) {
    const float* emb = (const float*)d_in[0];
    const int*   ei  = (const int*)d_in[1];
    const float* en  = (const float*)d_in[2];
    const float* lw  = (const float*)d_in[3];
    const float* lb  = (const float*)d_in[4];
    const float* sw  = (const float*)d_in[5];
    const float* sb  = (const float*)d_in[6];
    float* out = (float*)d_out;

    char* ws = (char*)d_ws;
    size_t o = 0;
    short8* B       = (short8*)(ws + o); o += 65536;
    int*    counts  = (int*)(ws + o);    o += 400128;
    int*    offsets = (int*)(ws + o);    o += 400128;   // N_NODES+1 entries
    int*    cursors = (int*)(ws + o);    o += 400128;
    int*    partials= (int*)(ws + o);    o += 1024;
    int2*   pairs   = (int2*)(ws + o);   o += (size_t)N_EDGES * 8;
    short*  zb      = (short*)(ws + o);  o += (size_t)N_NODES * OUT_CH * 2;
    int use_zb = (o <= ws_size) ? 1 : 0;

    hipMemsetAsync(counts, 0, N_NODES * sizeof(int), stream);
    hipMemsetAsync(cursors, 0, N_NODES * sizeof(int), stream);

    prep_b<<<16, 256, 0, stream>>>(lw, sw, B);
    hist_k<<<(N_EDGES + 255) / 256, 256, 0, stream>>>(ei, counts);
    scan1_k<<<98, 1024, 0, stream>>>(counts, offsets, partials);
    scan2_k<<<1, 64, 0, stream>>>(partials, 98, offsets);
    scan3_k<<<98, 1024, 0, stream>>>(offsets, partials);
    reorder_k<<<(N_EDGES + 255) / 256, 256, 0, stream>>>(ei, en, offsets, cursors, pairs);
    gather_k<<<(N_NODES * 64 + 255) / 256, 256, 0, stream>>>(emb, offsets, pairs, out);
    gemm_k<<<(N_NODES / 16 + 3) / 4, 256, 0, stream>>>(out, B, lb, sb, zb, use_zb);
    float* lg = out + (size_t)2 * N_NODES * OUT_CH;
    if (use_zb)
        logits_bf16_k<<<((size_t)N_EDGES * 16 + 255) / 256, 256, 0, stream>>>(
            (const short8*)zb, ei, lg);
    else
        logits_f32_k<<<((size_t)N_EDGES * 32 + 255) / 256, 256, 0, stream>>>(out, ei, lg);
}

// Round 6
// 243.379 us; speedup vs baseline: 1.2869x; 1.1549x over previous
//
#include <hip/hip_runtime.h>

#define N_NODES 100000
#define OUT_CH  128
#define N_EDGES 625000

typedef short short8 __attribute__((ext_vector_type(8)));
typedef float f32x4  __attribute__((ext_vector_type(4)));

__device__ inline short f32_bf16(float f) {
    union { float f; unsigned u; } c{f};
    unsigned r = 0x7FFFu + ((c.u >> 16) & 1u);
    return (short)((c.u + r) >> 16);
}
__device__ inline float bf16_f32(short s) {
    union { unsigned u; float f; } c;
    c.u = ((unsigned)(unsigned short)s) << 16;
    return c.f;
}
__device__ inline float sp_fast(float x) {   // softplus via hw exp2/log2
    float e = __expf(-fabsf(x));
    return fmaxf(x, 0.f) + __logf(1.f + e);
}

// ---- W fragments (loc_w | std_w fused). idx=lane&15 (channel in 16-tile),
// k = ks*32 + (lane>>4)*8 + j. Used as MFMA *A* operand. ----
__global__ void prep_b(const float* __restrict__ lw, const float* __restrict__ sw,
                       short8* __restrict__ B) {
    int g = blockIdx.x * blockDim.x + threadIdx.x;   // 4096 threads
    int lane = g & 63, nt = (g >> 6) & 15, ks = g >> 10;
    int c = nt * 16 + (lane & 15);
    int k = ks * 32 + (lane >> 4) * 8;
    const float* src = (c < OUT_CH) ? (lw + c * OUT_CH + k)
                                    : (sw + (c - OUT_CH) * OUT_CH + k);
    short8 o;
#pragma unroll
    for (int j = 0; j < 8; ++j) o[j] = f32_bf16(src[j]);
    B[(ks * 16 + nt) * 64 + lane] = o;
}

// ---- counting sort of edges by target node ----
__global__ void hist_k(const int* __restrict__ ei, int* __restrict__ counts) {
    int e = blockIdx.x * blockDim.x + threadIdx.x;
    if (e < N_EDGES) atomicAdd(&counts[ei[N_EDGES + e]], 1);
}

__global__ void scan1_k(const int* __restrict__ counts, int* __restrict__ offsets,
                        int* __restrict__ partials) {
    __shared__ int lds[1024];
    int tid = threadIdx.x;
    int e = blockIdx.x * 1024 + tid;
    int v = (e < N_NODES) ? counts[e] : 0;
    lds[tid] = v;
    __syncthreads();
    for (int off = 1; off < 1024; off <<= 1) {
        int t = (tid >= off) ? lds[tid - off] : 0;
        __syncthreads();
        lds[tid] += t;
        __syncthreads();
    }
    int incl = lds[tid];
    if (e < N_NODES) offsets[e] = incl - v;
    if (tid == 1023) partials[blockIdx.x] = incl;
}

// parallel 128-entry exclusive scan of block partials
__global__ void scan2_k(int* __restrict__ partials, int nb, int* __restrict__ offsets) {
    __shared__ int lds[128];
    int tid = threadIdx.x;
    int v = (tid < nb) ? partials[tid] : 0;
    lds[tid] = v;
    __syncthreads();
    for (int off = 1; off < 128; off <<= 1) {
        int t = (tid >= off) ? lds[tid - off] : 0;
        __syncthreads();
        lds[tid] += t;
        __syncthreads();
    }
    if (tid < nb) partials[tid] = lds[tid] - v;
    if (tid == 0) offsets[N_NODES] = N_EDGES;
}

__global__ void scan3_k(int* __restrict__ offsets, const int* __restrict__ partials) {
    int e = blockIdx.x * 1024 + threadIdx.x;
    if (e < N_NODES) offsets[e] += partials[blockIdx.x];
}

__global__ void reorder_k(const int* __restrict__ ei, const float* __restrict__ en,
                          const int* __restrict__ offsets, int* __restrict__ cursors,
                          int2* __restrict__ pairs) {
    int e = blockIdx.x * blockDim.x + threadIdx.x;
    if (e >= N_EDGES) return;
    int t = ei[N_EDGES + e];
    int pos = offsets[t] + atomicAdd(&cursors[t], 1);
    int2 p; p.x = ei[e]; p.y = __float_as_int(en[e]);
    pairs[pos] = p;
}

// ---- segment-sum gather: one wave per node, x4 unrolled (MLP) ----
__global__ void gather_k(const float* __restrict__ emb, const int* __restrict__ offsets,
                         const int2* __restrict__ pairs, float* __restrict__ ptrb) {
    int g = blockIdx.x * blockDim.x + threadIdx.x;
    int node = g >> 6, lane = g & 63;
    if (node >= N_NODES) return;
    int beg = offsets[node], end = offsets[node + 1];
    float ax = 0.f, ay = 0.f;
    const float2* base = (const float2*)emb;
    int j = beg;
    for (; j + 4 <= end; j += 4) {
        int2 p0 = pairs[j], p1 = pairs[j + 1], p2 = pairs[j + 2], p3 = pairs[j + 3];
        float2 v0 = base[(size_t)p0.x * 64 + lane];
        float2 v1 = base[(size_t)p1.x * 64 + lane];
        float2 v2 = base[(size_t)p2.x * 64 + lane];
        float2 v3 = base[(size_t)p3.x * 64 + lane];
        float n0f = __int_as_float(p0.y), n1f = __int_as_float(p1.y);
        float n2f = __int_as_float(p2.y), n3f = __int_as_float(p3.y);
        ax += v0.x * n0f + v1.x * n1f + v2.x * n2f + v3.x * n3f;
        ay += v0.y * n0f + v1.y * n1f + v2.y * n2f + v3.y * n3f;
    }
    for (; j < end; ++j) {
        int2 p = pairs[j];
        float nm = __int_as_float(p.y);
        float2 v = base[(size_t)p.x * 64 + lane];
        ax += v.x * nm; ay += v.y * nm;
    }
    float2 o; o.x = ax; o.y = ay;
    ((float2*)ptrb)[(size_t)node * 64 + lane] = o;
}

// ---- loc/std GEMM: reads P (ws ptr buffer), writes loc/std/zb. No aliasing
// when P != out. D=[channel][node]: lane stores 4 consecutive channels. ----
__global__ __launch_bounds__(256) void gemm_k(const float* __restrict__ P,
                                              float* __restrict__ out,
                                              const short8* __restrict__ B,
                                              const float* __restrict__ lb,
                                              const float* __restrict__ sb,
                                              short* __restrict__ zb, int write_zb) {
    int tid = threadIdx.x;
    int wave = tid >> 6, lane = tid & 63;
    int n0 = (blockIdx.x * 4 + wave) * 16;
    if (n0 >= N_NODES) return;

    float* loc  = out;
    float* stdo = out + (size_t)N_NODES * OUT_CH;

    int prow = n0 + (lane & 15);       // node this lane supplies (B col) & stores
    int kb = (lane >> 4) * 8;

    f32x4 acc[16];
#pragma unroll
    for (int i = 0; i < 16; ++i) acc[i] = (f32x4)(0.f);

#pragma unroll
    for (int ks = 0; ks < 4; ++ks) {
        const float* ap = P + (size_t)prow * OUT_CH + ks * 32 + kb;
        float4 a0 = *(const float4*)ap;
        float4 a1 = *(const float4*)(ap + 4);
        short8 a;
        a[0] = f32_bf16(a0.x); a[1] = f32_bf16(a0.y);
        a[2] = f32_bf16(a0.z); a[3] = f32_bf16(a0.w);
        a[4] = f32_bf16(a1.x); a[5] = f32_bf16(a1.y);
        a[6] = f32_bf16(a1.z); a[7] = f32_bf16(a1.w);
#pragma unroll
        for (int nt = 0; nt < 16; ++nt) {
            short8 w = B[(ks * 16 + nt) * 64 + lane];
            // A = weights (row=channel), B = ptr rows (col=node)
            acc[nt] = __builtin_amdgcn_mfma_f32_16x16x32_bf16(w, a, acc[nt], 0, 0, 0);
        }
    }

    int node = n0 + (lane & 15);
    int ch4 = (lane >> 4) * 4;         // C/D: row = (lane>>4)*4 + reg = channel
    float* lrow = loc  + (size_t)node * OUT_CH;
    float* srow = stdo + (size_t)node * OUT_CH;
    short* zrow = zb   + (size_t)node * OUT_CH;

#pragma unroll
    for (int nt = 0; nt < 8; ++nt) {   // loc tiles: channels 0..127
        int c = nt * 16 + ch4;
        float4 b4 = *(const float4*)(lb + c);
        float4 v;
        v.x = acc[nt][0] + b4.x; v.y = acc[nt][1] + b4.y;
        v.z = acc[nt][2] + b4.z; v.w = acc[nt][3] + b4.w;
        *(float4*)(lrow + c) = v;
        if (write_zb) {
            short4 zs;
            zs.x = f32_bf16(v.x); zs.y = f32_bf16(v.y);
            zs.z = f32_bf16(v.z); zs.w = f32_bf16(v.w);
            *(short4*)(zrow + c) = zs;
        }
    }
#pragma unroll
    for (int nt = 8; nt < 16; ++nt) {  // std tiles: channels 128..255
        int cc = nt * 16 + ch4 - OUT_CH;
        float4 b4 = *(const float4*)(sb + cc);
        float4 v;
        v.x = sp_fast(acc[nt][0] + b4.x) + 1e-10f;
        v.y = sp_fast(acc[nt][1] + b4.y) + 1e-10f;
        v.z = sp_fast(acc[nt][2] + b4.z) + 1e-10f;
        v.w = sp_fast(acc[nt][3] + b4.w) + 1e-10f;
        *(float4*)(srow + cc) = v;
    }
}

// ---- logits from bf16 z: 16 lanes/edge, one 16B load per side ----
__global__ void logits_bf16_k(const short8* __restrict__ z, const int* __restrict__ ei,
                              float* __restrict__ lg) {
    int idx = blockIdx.x * blockDim.x + threadIdx.x;
    int e = idx >> 4, q = idx & 15;
    if (e >= N_EDGES) return;
    int s = ei[e], t = ei[N_EDGES + e];
    short8 a = z[(size_t)s * 16 + q];
    short8 b = z[(size_t)t * 16 + q];
    float d = 0.f;
#pragma unroll
    for (int i = 0; i < 8; ++i) d += bf16_f32(a[i]) * bf16_f32(b[i]);
#pragma unroll
    for (int m = 8; m >= 1; m >>= 1) d += __shfl_xor(d, m);
    if (q == 0) lg[e] = d;
}

// ---- fallback: logits from f32 loc ----
__global__ void logits_f32_k(const float* __restrict__ z, const int* __restrict__ ei,
                             float* __restrict__ lg) {
    int idx = blockIdx.x * blockDim.x + threadIdx.x;
    int e = idx >> 5, q = idx & 31;
    if (e >= N_EDGES) return;
    int s = ei[e], t = ei[N_EDGES + e];
    float4 a = *(const float4*)(z + (size_t)s * OUT_CH + q * 4);
    float4 b = *(const float4*)(z + (size_t)t * OUT_CH + q * 4);
    float d = a.x * b.x + a.y * b.y + a.z * b.z + a.w * b.w;
#pragma unroll
    for (int m = 16; m >= 1; m >>= 1) d += __shfl_xor(d, m);
    if (q == 0) lg[e] = d;
}

extern "C" void kernel_launch(void* const* d_in, const int* in_sizes, int n_in,
                              void* d_out, int out_size, void* d_ws, size_t ws_size,
                              hipStream_t stream) {
    const float* emb = (const float*)d_in[0];
    const int*   ei  = (const int*)d_in[1];
    const float* en  = (const float*)d_in[2];
    const float* lw  = (const float*)d_in[3];
    const float* lb  = (const float*)d_in[4];
    const float* sw  = (const float*)d_in[5];
    const float* sb  = (const float*)d_in[6];
    float* out = (float*)d_out;

    char* ws = (char*)d_ws;
    size_t o = 0;
    short8* B       = (short8*)(ws + o); o += 65536;
    int*    counts  = (int*)(ws + o);    o += 400128;
    int*    offsets = (int*)(ws + o);    o += 400128;   // N_NODES+1 entries
    int*    cursors = (int*)(ws + o);    o += 400128;
    int*    partials= (int*)(ws + o);    o += 1024;
    int2*   pairs   = (int2*)(ws + o);   o += (size_t)N_EDGES * 8;

    // ptr accumulator in ws (priority 1): removes gemm in-place aliasing
    float* ptr_ws = (float*)(ws + o);
    size_t o_ptr = o + (size_t)N_NODES * OUT_CH * 4;
    int use_pw = (o_ptr <= ws_size) ? 1 : 0;
    size_t o_zb0 = use_pw ? o_ptr : o;

    // bf16 z copy (priority 2): faster logits
    short* zb = (short*)(ws + o_zb0);
    size_t o_zb = o_zb0 + (size_t)N_NODES * OUT_CH * 2;
    int use_zb = (o_zb <= ws_size) ? 1 : 0;

    float* P = use_pw ? ptr_ws : out;   // fallback: in-place over loc region

    hipMemsetAsync(counts, 0, N_NODES * sizeof(int), stream);
    hipMemsetAsync(cursors, 0, N_NODES * sizeof(int), stream);

    prep_b<<<16, 256, 0, stream>>>(lw, sw, B);
    hist_k<<<(N_EDGES + 255) / 256, 256, 0, stream>>>(ei, counts);
    scan1_k<<<98, 1024, 0, stream>>>(counts, offsets, partials);
    scan2_k<<<1, 128, 0, stream>>>(partials, 98, offsets);
    scan3_k<<<98, 1024, 0, stream>>>(offsets, partials);
    reorder_k<<<(N_EDGES + 255) / 256, 256, 0, stream>>>(ei, en, offsets, cursors, pairs);
    gather_k<<<(N_NODES * 64 + 255) / 256, 256, 0, stream>>>(emb, offsets, pairs, P);
    gemm_k<<<(N_NODES / 16 + 3) / 4, 256, 0, stream>>>(P, out, B, lb, sb, zb, use_zb);
    float* lg = out + (size_t)2 * N_NODES * OUT_CH;
    if (use_zb)
        logits_bf16_k<<<((size_t)N_EDGES * 16 + 255) / 256, 256, 0, stream>>>(
            (const short8*)zb, ei, lg);
    else
        logits_f32_k<<<((size_t)N_EDGES * 32 + 255) / 256, 256, 0, stream>>>(out, ei, lg);
}

// Round 7
// 222.586 us; speedup vs baseline: 1.4071x; 1.0934x over previous
//
#include <hip/hip_runtime.h>

#define N_NODES 100000
#define OUT_CH  128
#define N_EDGES 625000

typedef short short8 __attribute__((ext_vector_type(8)));
typedef float f32x4  __attribute__((ext_vector_type(4)));

__device__ inline short f32_bf16(float f) {
    union { float f; unsigned u; } c{f};
    unsigned r = 0x7FFFu + ((c.u >> 16) & 1u);
    return (short)((c.u + r) >> 16);
}
__device__ inline float bf16_f32(short s) {
    union { unsigned u; float f; } c;
    c.u = ((unsigned)(unsigned short)s) << 16;
    return c.f;
}
__device__ inline float sp_fast(float x) {   // softplus via hw exp/log
    float e = __expf(-fabsf(x));
    return fmaxf(x, 0.f) + __logf(1.f + e);
}

// ---- W fragments (loc_w | std_w fused). idx=lane&15 (channel in 16-tile),
// k = ks*32 + (lane>>4)*8 + j. Used as MFMA *A* operand. ----
__global__ void prep_b(const float* __restrict__ lw, const float* __restrict__ sw,
                       short8* __restrict__ B) {
    int g = blockIdx.x * blockDim.x + threadIdx.x;   // 4096 threads
    int lane = g & 63, nt = (g >> 6) & 15, ks = g >> 10;
    int c = nt * 16 + (lane & 15);
    int k = ks * 32 + (lane >> 4) * 8;
    const float* src = (c < OUT_CH) ? (lw + c * OUT_CH + k)
                                    : (sw + (c - OUT_CH) * OUT_CH + k);
    short8 o;
#pragma unroll
    for (int j = 0; j < 8; ++j) o[j] = f32_bf16(src[j]);
    B[(ks * 16 + nt) * 64 + lane] = o;
}

// ---- counting sort of edges by target node ----
__global__ void hist_k(const int* __restrict__ ei, int* __restrict__ counts) {
    int e = blockIdx.x * blockDim.x + threadIdx.x;
    if (e < N_EDGES) atomicAdd(&counts[ei[N_EDGES + e]], 1);
}

__global__ void scan1_k(const int* __restrict__ counts, int* __restrict__ offsets,
                        int* __restrict__ partials) {
    __shared__ int lds[1024];
    int tid = threadIdx.x;
    int e = blockIdx.x * 1024 + tid;
    int v = (e < N_NODES) ? counts[e] : 0;
    lds[tid] = v;
    __syncthreads();
    for (int off = 1; off < 1024; off <<= 1) {
        int t = (tid >= off) ? lds[tid - off] : 0;
        __syncthreads();
        lds[tid] += t;
        __syncthreads();
    }
    int incl = lds[tid];
    if (e < N_NODES) offsets[e] = incl - v;
    if (tid == 1023) partials[blockIdx.x] = incl;
}

__global__ void scan2_k(int* __restrict__ partials, int nb, int* __restrict__ offsets) {
    __shared__ int lds[128];
    int tid = threadIdx.x;
    int v = (tid < nb) ? partials[tid] : 0;
    lds[tid] = v;
    __syncthreads();
    for (int off = 1; off < 128; off <<= 1) {
        int t = (tid >= off) ? lds[tid - off] : 0;
        __syncthreads();
        lds[tid] += t;
        __syncthreads();
    }
    if (tid < nb) partials[tid] = lds[tid] - v;
    if (tid == 0) offsets[N_NODES] = N_EDGES;
}

__global__ void scan3_k(int* __restrict__ offsets, const int* __restrict__ partials) {
    int e = blockIdx.x * 1024 + threadIdx.x;
    if (e < N_NODES) offsets[e] += partials[blockIdx.x];
}

// writes pairs=(src, norm) for gather and et=(orig_e, t) for sorted logits
__global__ void reorder_k(const int* __restrict__ ei, const float* __restrict__ en,
                          const int* __restrict__ offsets, int* __restrict__ cursors,
                          int2* __restrict__ pairs, int2* __restrict__ et) {
    int e = blockIdx.x * blockDim.x + threadIdx.x;
    if (e >= N_EDGES) return;
    int t = ei[N_EDGES + e];
    int pos = offsets[t] + atomicAdd(&cursors[t], 1);
    int2 p; p.x = ei[e]; p.y = __float_as_int(en[e]);
    pairs[pos] = p;
    int2 q; q.x = e; q.y = t;
    et[pos] = q;
}

// ---- segment-sum gather: one wave per node, clamp-predicated x8 so every
// iteration issues 8 independent loads (no serial remainder chain).
// Emits bf16 ptr directly (rounding point identical to previous gemm cvt). ----
__global__ void gather_k(const float* __restrict__ emb, const int* __restrict__ offsets,
                         const int2* __restrict__ pairs, short* __restrict__ ptrb) {
    int g = blockIdx.x * blockDim.x + threadIdx.x;
    int node = g >> 6, lane = g & 63;
    if (node >= N_NODES) return;
    int beg = offsets[node], end = offsets[node + 1];
    float ax = 0.f, ay = 0.f;
    const float2* base = (const float2*)emb;
    int last = end - 1;
    for (int j = beg; j < end; j += 8) {
        float2 v[8]; float nm[8];
#pragma unroll
        for (int i = 0; i < 8; ++i) {
            int jj = j + i;
            int jc = (jj < end) ? jj : last;
            int2 p = pairs[jc];
            v[i] = base[(size_t)p.x * 64 + lane];
            nm[i] = (jj < end) ? __int_as_float(p.y) : 0.f;
        }
#pragma unroll
        for (int i = 0; i < 8; ++i) { ax += v[i].x * nm[i]; ay += v[i].y * nm[i]; }
    }
    ushort2 o; o.x = (unsigned short)f32_bf16(ax); o.y = (unsigned short)f32_bf16(ay);
    ((ushort2*)ptrb)[(size_t)node * 64 + lane] = o;
}

// ---- loc/std GEMM: reads bf16 P (ws), writes loc/std f32 + bf16 z.
// D=[channel][node]: each lane stores 4 consecutive channels of one node. ----
__global__ __launch_bounds__(256) void gemm_k(const short* __restrict__ P,
                                              float* __restrict__ out,
                                              const short8* __restrict__ B,
                                              const float* __restrict__ lb,
                                              const float* __restrict__ sb,
                                              short* __restrict__ zb, int write_zb) {
    int tid = threadIdx.x;
    int wave = tid >> 6, lane = tid & 63;
    int n0 = (blockIdx.x * 4 + wave) * 16;
    if (n0 >= N_NODES) return;

    float* loc  = out;
    float* stdo = out + (size_t)N_NODES * OUT_CH;

    int prow = n0 + (lane & 15);       // node this lane supplies (B col) & stores
    int kb = (lane >> 4) * 8;

    f32x4 acc[16];
#pragma unroll
    for (int i = 0; i < 16; ++i) acc[i] = (f32x4)(0.f);

#pragma unroll
    for (int ks = 0; ks < 4; ++ks) {
        short8 a = *(const short8*)(P + (size_t)prow * OUT_CH + ks * 32 + kb);
#pragma unroll
        for (int nt = 0; nt < 16; ++nt) {
            short8 w = B[(ks * 16 + nt) * 64 + lane];
            // A = weights (row=channel), B = ptr rows (col=node)
            acc[nt] = __builtin_amdgcn_mfma_f32_16x16x32_bf16(w, a, acc[nt], 0, 0, 0);
        }
    }

    int node = n0 + (lane & 15);
    int ch4 = (lane >> 4) * 4;         // C/D: row = (lane>>4)*4 + reg = channel
    float* lrow = loc  + (size_t)node * OUT_CH;
    float* srow = stdo + (size_t)node * OUT_CH;
    short* zrow = zb   + (size_t)node * OUT_CH;

#pragma unroll
    for (int nt = 0; nt < 8; ++nt) {   // loc tiles: channels 0..127
        int c = nt * 16 + ch4;
        float4 b4 = *(const float4*)(lb + c);
        float4 v;
        v.x = acc[nt][0] + b4.x; v.y = acc[nt][1] + b4.y;
        v.z = acc[nt][2] + b4.z; v.w = acc[nt][3] + b4.w;
        *(float4*)(lrow + c) = v;
        if (write_zb) {
            short4 zs;
            zs.x = f32_bf16(v.x); zs.y = f32_bf16(v.y);
            zs.z = f32_bf16(v.z); zs.w = f32_bf16(v.w);
            *(short4*)(zrow + c) = zs;
        }
    }
#pragma unroll
    for (int nt = 8; nt < 16; ++nt) {  // std tiles: channels 128..255
        int cc = nt * 16 + ch4 - OUT_CH;
        float4 b4 = *(const float4*)(sb + cc);
        float4 v;
        v.x = sp_fast(acc[nt][0] + b4.x) + 1e-10f;
        v.y = sp_fast(acc[nt][1] + b4.y) + 1e-10f;
        v.z = sp_fast(acc[nt][2] + b4.z) + 1e-10f;
        v.w = sp_fast(acc[nt][3] + b4.w) + 1e-10f;
        *(float4*)(srow + cc) = v;
    }
}

// ---- logits in t-sorted order: consecutive edges share t -> L1/L2 reuse.
// 16 lanes/edge; pair metadata loads are wave-broadcast. ----
__global__ void logits_srt_k(const short8* __restrict__ z,
                             const int2* __restrict__ pairs,
                             const int2* __restrict__ et,
                             float* __restrict__ lg) {
    int idx = blockIdx.x * blockDim.x + threadIdx.x;
    int p = idx >> 4, q = idx & 15;
    if (p >= N_EDGES) return;
    int s = pairs[p].x;
    int2 me = et[p];
    short8 a = z[(size_t)s * 16 + q];
    short8 b = z[(size_t)me.y * 16 + q];
    float d = 0.f;
#pragma unroll
    for (int i = 0; i < 8; ++i) d += bf16_f32(a[i]) * bf16_f32(b[i]);
#pragma unroll
    for (int m = 8; m >= 1; m >>= 1) d += __shfl_xor(d, m);
    if (q == 0) lg[me.x] = d;
}

// ---- fallback: logits from f32 loc, original edge order ----
__global__ void logits_f32_k(const float* __restrict__ z, const int* __restrict__ ei,
                             float* __restrict__ lg) {
    int idx = blockIdx.x * blockDim.x + threadIdx.x;
    int e = idx >> 5, q = idx & 31;
    if (e >= N_EDGES) return;
    int s = ei[e], t = ei[N_EDGES + e];
    float4 a = *(const float4*)(z + (size_t)s * OUT_CH + q * 4);
    float4 b = *(const float4*)(z + (size_t)t * OUT_CH + q * 4);
    float d = a.x * b.x + a.y * b.y + a.z * b.z + a.w * b.w;
#pragma unroll
    for (int m = 16; m >= 1; m >>= 1) d += __shfl_xor(d, m);
    if (q == 0) lg[e] = d;
}

extern "C" void kernel_launch(void* const* d_in, const int* in_sizes, int n_in,
                              void* d_out, int out_size, void* d_ws, size_t ws_size,
                              hipStream_t stream) {
    const float* emb = (const float*)d_in[0];
    const int*   ei  = (const int*)d_in[1];
    const float* en  = (const float*)d_in[2];
    const float* lw  = (const float*)d_in[3];
    const float* lb  = (const float*)d_in[4];
    const float* sw  = (const float*)d_in[5];
    const float* sb  = (const float*)d_in[6];
    float* out = (float*)d_out;

    char* ws = (char*)d_ws;
    size_t o = 0;
    short8* B       = (short8*)(ws + o); o += 65536;
    int*    counts  = (int*)(ws + o);    o += 400128;
    int*    offsets = (int*)(ws + o);    o += 400128;   // N_NODES+1 entries
    int*    cursors = (int*)(ws + o);    o += 400128;
    int*    partials= (int*)(ws + o);    o += 1024;
    int2*   pairs   = (int2*)(ws + o);   o += (size_t)N_EDGES * 8;
    int2*   et      = (int2*)(ws + o);   o += (size_t)N_EDGES * 8;
    short*  ptrb    = (short*)(ws + o);  o += (size_t)N_NODES * OUT_CH * 2;  // bf16 ptr

    // bf16 z copy for fast logits (optional)
    short* zb = (short*)(ws + o);
    size_t o_zb = o + (size_t)N_NODES * OUT_CH * 2;
    int use_zb = (o_zb <= ws_size) ? 1 : 0;

    hipMemsetAsync(counts, 0, N_NODES * sizeof(int), stream);
    hipMemsetAsync(cursors, 0, N_NODES * sizeof(int), stream);

    prep_b<<<16, 256, 0, stream>>>(lw, sw, B);
    hist_k<<<(N_EDGES + 255) / 256, 256, 0, stream>>>(ei, counts);
    scan1_k<<<98, 1024, 0, stream>>>(counts, offsets, partials);
    scan2_k<<<1, 128, 0, stream>>>(partials, 98, offsets);
    scan3_k<<<98, 1024, 0, stream>>>(offsets, partials);
    reorder_k<<<(N_EDGES + 255) / 256, 256, 0, stream>>>(ei, en, offsets, cursors,
                                                         pairs, et);
    gather_k<<<(N_NODES * 64 + 255) / 256, 256, 0, stream>>>(emb, offsets, pairs, ptrb);
    gemm_k<<<(N_NODES / 16 + 3) / 4, 256, 0, stream>>>(ptrb, out, B, lb, sb, zb, use_zb);
    float* lg = out + (size_t)2 * N_NODES * OUT_CH;
    if (use_zb)
        logits_srt_k<<<((size_t)N_EDGES * 16 + 255) / 256, 256, 0, stream>>>(
            (const short8*)zb, pairs, et, lg);
    else
        logits_f32_k<<<((size_t)N_EDGES * 32 + 255) / 256, 256, 0, stream>>>(out, ei, lg);
}